// Round 2
// baseline (272.736 us; speedup 1.0000x reference)
//
#include <hip/hip_runtime.h>
#include <math.h>

#define BATCH 4096
#define NFEAT 4
#define VOCAB 100000
#define EMB 64
#define D_IN 256
#define D_H 256
#define D_O 128
#define ROWS 32  // rows per block in tower kernel

// ---------------------------------------------------------------------------
// Fused tower: gather -> MLP(256->256 relu -> 128 relu) -> L2-normalize rows.
// Grid: (BATCH/ROWS, 2). 256 threads. Writes normalized rows to U or V.
// Thread layout for GEMMs: tx = tid&63 -> 4 (layer1) / 2 (layer2) contiguous
// cols; wave w = tid>>6 -> 8 rows. Xs/Hs reads are wave-uniform broadcasts.
// ---------------------------------------------------------------------------
__global__ __launch_bounds__(256) void tower_kernel(
    const int* __restrict__ user_ids, const int* __restrict__ item_ids,
    const float* __restrict__ user_tables, const float* __restrict__ item_tables,
    const float* __restrict__ uW1, const float* __restrict__ ub1,
    const float* __restrict__ uW2, const float* __restrict__ ub2,
    const float* __restrict__ iW1, const float* __restrict__ ib1,
    const float* __restrict__ iW2, const float* __restrict__ ib2,
    float* __restrict__ U, float* __restrict__ V) {
  const int tower = blockIdx.y;
  const int* ids = tower ? item_ids : user_ids;
  const float* tab = tower ? item_tables : user_tables;
  const float* W1 = tower ? iW1 : uW1;
  const float* b1 = tower ? ib1 : ub1;
  const float* W2 = tower ? iW2 : uW2;
  const float* b2 = tower ? ib2 : ub2;
  float* O = tower ? V : U;

  const int r0 = blockIdx.x * ROWS;
  const int tid = threadIdx.x;

  __shared__ float Xs[ROWS][D_IN];
  __shared__ float Hs[ROWS][D_H];

  // ---- gather: 32 rows x 64 float4 slots = 2048 slots, 8 per thread ----
#pragma unroll
  for (int i = 0; i < 8; i++) {
    int slot = i * 256 + tid;
    int row = slot >> 6;
    int c4 = slot & 63;
    int f = c4 >> 4;
    int id = ids[(size_t)(r0 + row) * NFEAT + f];
    const float4* src = (const float4*)(tab + ((size_t)f * VOCAB + (size_t)id) * EMB);
    *(float4*)&Xs[row][c4 * 4] = src[c4 & 15];
  }
  __syncthreads();

  const int tx = tid & 63;
  const int w = tid >> 6;

  // ---- layer 1: H[32][256] = relu(X @ W1 + b1) ----
  {
    const int c0 = tx * 4;
    float acc[8][4];
    float4 bb = *(const float4*)(b1 + c0);
#pragma unroll
    for (int r = 0; r < 8; r++) {
      acc[r][0] = bb.x; acc[r][1] = bb.y; acc[r][2] = bb.z; acc[r][3] = bb.w;
    }
    for (int k = 0; k < D_IN; k += 4) {
      float4 wv[4];
#pragma unroll
      for (int kk = 0; kk < 4; kk++)
        wv[kk] = *(const float4*)(W1 + (size_t)(k + kk) * D_H + c0);
      float4 xv[8];
#pragma unroll
      for (int r = 0; r < 8; r++)
        xv[r] = *(const float4*)&Xs[w * 8 + r][k];
#pragma unroll
      for (int r = 0; r < 8; r++) {
        const float* xp = (const float*)&xv[r];
#pragma unroll
        for (int kk = 0; kk < 4; kk++) {
          const float* wp = (const float*)&wv[kk];
          float a = xp[kk];
#pragma unroll
          for (int j = 0; j < 4; j++) acc[r][j] += a * wp[j];
        }
      }
    }
#pragma unroll
    for (int r = 0; r < 8; r++) {
      float4 o;
      o.x = fmaxf(acc[r][0], 0.f); o.y = fmaxf(acc[r][1], 0.f);
      o.z = fmaxf(acc[r][2], 0.f); o.w = fmaxf(acc[r][3], 0.f);
      *(float4*)&Hs[w * 8 + r][c0] = o;
    }
  }
  __syncthreads();

  // ---- layer 2: Y[32][128] = relu(H @ W2 + b2), then row-normalize ----
  {
    const int c0 = tx * 2;
    float acc[8][2];
    float2 bb = *(const float2*)(b2 + c0);
#pragma unroll
    for (int r = 0; r < 8; r++) { acc[r][0] = bb.x; acc[r][1] = bb.y; }
    for (int k = 0; k < D_H; k += 4) {
      float2 wv[4];
#pragma unroll
      for (int kk = 0; kk < 4; kk++)
        wv[kk] = *(const float2*)(W2 + (size_t)(k + kk) * D_O + c0);
      float4 xv[8];
#pragma unroll
      for (int r = 0; r < 8; r++)
        xv[r] = *(const float4*)&Hs[w * 8 + r][k];
#pragma unroll
      for (int r = 0; r < 8; r++) {
        const float* xp = (const float*)&xv[r];
#pragma unroll
        for (int kk = 0; kk < 4; kk++) {
          acc[r][0] += xp[kk] * wv[kk].x;
          acc[r][1] += xp[kk] * wv[kk].y;
        }
      }
    }
    // relu + per-row L2 norm (wave w owns all 128 cols of its 8 rows)
#pragma unroll
    for (int r = 0; r < 8; r++) {
      float y0 = fmaxf(acc[r][0], 0.f);
      float y1 = fmaxf(acc[r][1], 0.f);
      float s = y0 * y0 + y1 * y1;
#pragma unroll
      for (int off = 32; off; off >>= 1) s += __shfl_xor(s, off);
      float inv = 1.f / fmaxf(sqrtf(s), 1e-8f);
      float2 o; o.x = y0 * inv; o.y = y1 * inv;
      *(float2*)(O + (size_t)(r0 + w * 8 + r) * D_O + c0) = o;
    }
  }
}

// ---------------------------------------------------------------------------
// Scores on pre-normalized U,V: out[i][j] = dot(un_i, vn_c) - log(sw[c]),
// c = (i+j) % B. One wave per row.
// ---------------------------------------------------------------------------
__global__ __launch_bounds__(256) void score_kernel(
    const float* __restrict__ U, const float* __restrict__ V,
    const int* __restrict__ sw_ids, const float* __restrict__ sw_table,
    float* __restrict__ out) {
  int wave = threadIdx.x >> 6;
  int lane = threadIdx.x & 63;
  int i = blockIdx.x * 4 + wave;

  float u0 = U[(size_t)i * D_O + lane];
  float u1 = U[(size_t)i * D_O + 64 + lane];

#pragma unroll
  for (int j = 0; j < 4; j++) {
    int c = (i + j) & (BATCH - 1);
    float v0 = V[(size_t)c * D_O + lane];
    float v1 = V[(size_t)c * D_O + 64 + lane];
    float d = u0 * v0 + u1 * v1;
#pragma unroll
    for (int off = 32; off; off >>= 1) d += __shfl_xor(d, off);
    if (lane == 0) {
      out[(size_t)i * 4 + j] = d - logf(sw_table[sw_ids[c]]);
    }
  }
}

extern "C" void kernel_launch(void* const* d_in, const int* in_sizes, int n_in,
                              void* d_out, int out_size, void* d_ws, size_t ws_size,
                              hipStream_t stream) {
  (void)in_sizes; (void)n_in; (void)out_size; (void)ws_size;
  const int*   user_ids    = (const int*)d_in[0];
  const int*   item_ids    = (const int*)d_in[1];
  const int*   sw_ids      = (const int*)d_in[2];
  const float* user_tables = (const float*)d_in[3];
  const float* item_tables = (const float*)d_in[4];
  const float* sw_table    = (const float*)d_in[5];
  const float* uW1 = (const float*)d_in[6];
  const float* ub1 = (const float*)d_in[7];
  const float* uW2 = (const float*)d_in[8];
  const float* ub2 = (const float*)d_in[9];
  const float* iW1 = (const float*)d_in[10];
  const float* ib1 = (const float*)d_in[11];
  const float* iW2 = (const float*)d_in[12];
  const float* ib2 = (const float*)d_in[13];
  float* out = (float*)d_out;

  float* U = (float*)d_ws;                // [B,128] normalized user vecs
  float* V = U + (size_t)BATCH * D_O;     // [B,128] normalized item vecs

  tower_kernel<<<dim3(BATCH / ROWS, 2), 256, 0, stream>>>(
      user_ids, item_ids, user_tables, item_tables,
      uW1, ub1, uW2, ub2, iW1, ib1, iW2, ib2, U, V);

  score_kernel<<<BATCH / 4, 256, 0, stream>>>(U, V, sw_ids, sw_table, out);
}

// Round 3
// 216.137 us; speedup vs baseline: 1.2619x; 1.2619x over previous
//
#include <hip/hip_runtime.h>
#include <math.h>

#define BATCH 4096
#define NFEAT 4
#define VOCAB 100000
#define EMB 64
#define D_IN 256
#define D_H 256
#define D_O 128
#define ROWS 16            // rows per tower block
#define XS_STRIDE 264      // ushort stride for 256-wide bf16 rows (+8 pad -> 2-way only)
#define YS_STRIDE 132      // float stride for 128-wide fp32 rows

typedef __attribute__((ext_vector_type(8))) short bf16x8;
typedef __attribute__((ext_vector_type(4))) float f32x4;

__device__ inline ushort f2bf(float f) {
  union { float f; unsigned u; } v; v.f = f;
  unsigned u = v.u;
  return (ushort)((u + 0x7fffu + ((u >> 16) & 1u)) >> 16);  // RNE
}

// ---------------------------------------------------------------------------
// Prep: transpose + convert the four weight matrices to bf16 Wt[n][k].
// ---------------------------------------------------------------------------
__global__ __launch_bounds__(256) void prep_kernel(
    const float* __restrict__ uW1, const float* __restrict__ uW2,
    const float* __restrict__ iW1, const float* __restrict__ iW2,
    ushort* __restrict__ W1tu, ushort* __restrict__ W2tu,
    ushort* __restrict__ W1ti, ushort* __restrict__ W2ti) {
  int idx = blockIdx.x * 256 + threadIdx.x;  // 0 .. 196608
  if (idx < 65536) {
    int n = idx >> 8, k = idx & 255;
    W1tu[idx] = f2bf(uW1[k * 256 + n]);
  } else if (idx < 131072) {
    int j = idx - 65536; int n = j >> 8, k = j & 255;
    W1ti[j] = f2bf(iW1[k * 256 + n]);
  } else if (idx < 163840) {
    int j = idx - 131072; int n = j >> 8, k = j & 255;
    W2tu[j] = f2bf(uW2[k * 128 + n]);
  } else {
    int j = idx - 163840; int n = j >> 8, k = j & 255;
    W2ti[j] = f2bf(iW2[k * 128 + n]);
  }
}

// ---------------------------------------------------------------------------
// Fused tower, bf16 MFMA: gather -> L1(256->256 relu) -> L2(256->128 relu)
// -> row L2-normalize -> global U/V (fp32).
// Grid (BATCH/ROWS, 2), 256 threads (4 waves). MFMA 16x16x32:
//   A-frag: lane holds A[m=lane&15][k=quad*8+j]
//   B-frag: lane holds B[k=quad*8+j][n=lane&15]  (read from Wt[n][k] contiguously)
//   C/D   : lane holds D[row=quad*4+reg][col=lane&15]
// ---------------------------------------------------------------------------
__global__ __launch_bounds__(256) void tower_kernel(
    const int* __restrict__ user_ids, const int* __restrict__ item_ids,
    const float* __restrict__ user_tables, const float* __restrict__ item_tables,
    const ushort* __restrict__ W1tu, const float* __restrict__ ub1,
    const ushort* __restrict__ W2tu, const float* __restrict__ ub2,
    const ushort* __restrict__ W1ti, const float* __restrict__ ib1,
    const ushort* __restrict__ W2ti, const float* __restrict__ ib2,
    float* __restrict__ U, float* __restrict__ V) {
  const int tower = blockIdx.y;
  const int* ids = tower ? item_ids : user_ids;
  const float* tab = tower ? item_tables : user_tables;
  const ushort* W1t = tower ? W1ti : W1tu;
  const float* b1 = tower ? ib1 : ub1;
  const ushort* W2t = tower ? W2ti : W2tu;
  const float* b2 = tower ? ib2 : ub2;
  float* O = tower ? V : U;

  const int r0 = blockIdx.x * ROWS;
  const int tid = threadIdx.x;

  __shared__ ushort Xs[ROWS][XS_STRIDE];
  __shared__ ushort Hs[ROWS][XS_STRIDE];
  __shared__ float Ys[ROWS][YS_STRIDE];

  // ---- gather + bf16 convert: 16 rows x 64 float4 slots, 4 per thread ----
#pragma unroll
  for (int i = 0; i < 4; i++) {
    int slot = i * 256 + tid;
    int row = slot >> 6;
    int c4 = slot & 63;
    int f = c4 >> 4;
    int id = ids[(size_t)(r0 + row) * NFEAT + f];
    float4 v = ((const float4*)(tab + ((size_t)f * VOCAB + (size_t)id) * EMB))[c4 & 15];
    ushort4 o = {f2bf(v.x), f2bf(v.y), f2bf(v.z), f2bf(v.w)};
    *(ushort4*)&Xs[row][c4 * 4] = o;
  }
  __syncthreads();

  const int lane = tid & 63;
  const int w = tid >> 6;
  const int m = lane & 15;
  const int quad = lane >> 4;

  // ---- layer 1: Hs[16][256] = relu(Xs @ W1 + b1), wave w -> cols w*64..+63
  {
    bf16x8 a[8];
#pragma unroll
    for (int k0 = 0; k0 < 8; k0++)
      a[k0] = *(const bf16x8*)&Xs[m][k0 * 32 + quad * 8];
#pragma unroll
    for (int ct = 0; ct < 4; ct++) {
      int n = (w * 4 + ct) * 16 + m;
      const ushort* wp = W1t + (size_t)n * 256 + quad * 8;
      f32x4 acc = {0.f, 0.f, 0.f, 0.f};
#pragma unroll
      for (int k0 = 0; k0 < 8; k0++)
        acc = __builtin_amdgcn_mfma_f32_16x16x32_bf16(
            a[k0], *(const bf16x8*)(wp + k0 * 32), acc, 0, 0, 0);
      float bias = b1[n];
#pragma unroll
      for (int reg = 0; reg < 4; reg++) {
        int r = quad * 4 + reg;
        Hs[r][n] = f2bf(fmaxf(acc[reg] + bias, 0.f));
      }
    }
  }
  __syncthreads();

  // ---- layer 2: Ys[16][128] = relu(Hs @ W2 + b2), wave w -> cols w*32..+31
  {
    bf16x8 h[8];
#pragma unroll
    for (int k0 = 0; k0 < 8; k0++)
      h[k0] = *(const bf16x8*)&Hs[m][k0 * 32 + quad * 8];
#pragma unroll
    for (int ct = 0; ct < 2; ct++) {
      int n = (w * 2 + ct) * 16 + m;
      const ushort* wp = W2t + (size_t)n * 256 + quad * 8;
      f32x4 acc = {0.f, 0.f, 0.f, 0.f};
#pragma unroll
      for (int k0 = 0; k0 < 8; k0++)
        acc = __builtin_amdgcn_mfma_f32_16x16x32_bf16(
            h[k0], *(const bf16x8*)(wp + k0 * 32), acc, 0, 0, 0);
      float bias = b2[n];
#pragma unroll
      for (int reg = 0; reg < 4; reg++) {
        int r = quad * 4 + reg;
        Ys[r][n] = fmaxf(acc[reg] + bias, 0.f);
      }
    }
  }
  __syncthreads();

  // ---- row L2-normalize, 4 rows per wave, write fp32 U/V ----
#pragma unroll
  for (int rr = 0; rr < 4; rr++) {
    int row = w * 4 + rr;
    float y0 = Ys[row][lane];
    float y1 = Ys[row][64 + lane];
    float s = y0 * y0 + y1 * y1;
#pragma unroll
    for (int off = 32; off; off >>= 1) s += __shfl_xor(s, off);
    float inv = 1.f / fmaxf(sqrtf(s), 1e-8f);
    float* op = O + (size_t)(r0 + row) * D_O;
    op[lane] = y0 * inv;
    op[64 + lane] = y1 * inv;
  }
}

// ---------------------------------------------------------------------------
// Scores on pre-normalized U,V: out[i][j] = dot(un_i, vn_c) - log(sw[c]),
// c = (i+j) % B. One wave per row.
// ---------------------------------------------------------------------------
__global__ __launch_bounds__(256) void score_kernel(
    const float* __restrict__ U, const float* __restrict__ V,
    const int* __restrict__ sw_ids, const float* __restrict__ sw_table,
    float* __restrict__ out) {
  int wave = threadIdx.x >> 6;
  int lane = threadIdx.x & 63;
  int i = blockIdx.x * 4 + wave;

  float u0 = U[(size_t)i * D_O + lane];
  float u1 = U[(size_t)i * D_O + 64 + lane];

#pragma unroll
  for (int j = 0; j < 4; j++) {
    int c = (i + j) & (BATCH - 1);
    float v0 = V[(size_t)c * D_O + lane];
    float v1 = V[(size_t)c * D_O + 64 + lane];
    float d = u0 * v0 + u1 * v1;
#pragma unroll
    for (int off = 32; off; off >>= 1) d += __shfl_xor(d, off);
    if (lane == 0) {
      out[(size_t)i * 4 + j] = d - logf(sw_table[sw_ids[c]]);
    }
  }
}

extern "C" void kernel_launch(void* const* d_in, const int* in_sizes, int n_in,
                              void* d_out, int out_size, void* d_ws, size_t ws_size,
                              hipStream_t stream) {
  (void)in_sizes; (void)n_in; (void)out_size; (void)ws_size;
  const int*   user_ids    = (const int*)d_in[0];
  const int*   item_ids    = (const int*)d_in[1];
  const int*   sw_ids      = (const int*)d_in[2];
  const float* user_tables = (const float*)d_in[3];
  const float* item_tables = (const float*)d_in[4];
  const float* sw_table    = (const float*)d_in[5];
  const float* uW1 = (const float*)d_in[6];
  const float* ub1 = (const float*)d_in[7];
  const float* uW2 = (const float*)d_in[8];
  const float* ub2 = (const float*)d_in[9];
  const float* iW1 = (const float*)d_in[10];
  const float* ib1 = (const float*)d_in[11];
  const float* iW2 = (const float*)d_in[12];
  const float* ib2 = (const float*)d_in[13];
  float* out = (float*)d_out;

  // ws layout
  float* U = (float*)d_ws;                          // [B,128] fp32
  float* V = U + (size_t)BATCH * D_O;               // [B,128] fp32
  ushort* W1tu = (ushort*)(V + (size_t)BATCH * D_O);  // [256][256] bf16
  ushort* W1ti = W1tu + 256 * 256;                    // [256][256]
  ushort* W2tu = W1ti + 256 * 256;                    // [128][256]
  ushort* W2ti = W2tu + 128 * 256;                    // [128][256]

  prep_kernel<<<768, 256, 0, stream>>>(uW1, uW2, iW1, iW2, W1tu, W2tu, W1ti, W2ti);

  tower_kernel<<<dim3(BATCH / ROWS, 2), 256, 0, stream>>>(
      user_ids, item_ids, user_tables, item_tables,
      W1tu, ub1, W2tu, ub2, W1ti, ib1, W2ti, ib2, U, V);

  score_kernel<<<BATCH / 4, 256, 0, stream>>>(U, V, sw_ids, sw_table, out);
}